// Round 8
// baseline (1771.953 us; speedup 1.0000x reference)
//
#include <hip/hip_runtime.h>
#include <hip/hip_bf16.h>
#include <math.h>

// DecoderLSTM: B=16384, ENC=512, H=256, DE=32, T=64. f32 in/out (runtime-
// detected via b_lstm pattern; bf16 fallback kept).
// Persistent: 256 blocks x 1024 threads (16 waves), one block per 64-row tile.
// Precision: bf16x2 (hi/lo) A operand + hi/lo W_enc + hi/lo W_k (ks=0).
// R8: 16 waves/block, each wave owns 16 gate-cols (removes the s-split and
// halves per-wave register demand: acc 64, cst 16, hnv 16). Occupancy
// 8 -> 16 waves/CU (4/SIMD) for latency hiding; 3 barriers/step (ybuf
// replaced by a 16-lane shuffle butterfly; x-update inlined).

typedef __bf16 bf16x8 __attribute__((ext_vector_type(8)));
typedef __bf16 bf16x2 __attribute__((ext_vector_type(2)));
typedef float f32x4 __attribute__((ext_vector_type(4)));

#define DEV __device__ __forceinline__

constexpr int ENC = 512;
constexpr int HD  = 256;
constexpr int DE  = 32;
constexpr int TT  = 64;
constexpr int NG  = 4 * HD;    // 1024 gate cols
constexpr int NKT = 9;         // K tiles (288 / 32)
constexpr int TS  = 528;       // frag tile stride elems (64*8 + 16 pad)

DEV bool is_f32(const void* blstm) {
  return ((const unsigned*)blstm)[256] == 0x3F800000u;
}
DEV float ldf(const void* p, size_t i, bool f32) {
  return f32 ? ((const float*)p)[i]
             : __bfloat162float(((const __hip_bfloat16*)p)[i]);
}
DEV void split2(float v, __hip_bfloat16& hi, __hip_bfloat16& lo) {
  hi = __float2bfloat16(v);
  lo = __float2bfloat16(v - __bfloat162float(hi));
}
DEV void ld8cvt2(const void* p, size_t i, bool f32, bf16x8& hi, bf16x8& lo) {
  if (f32) {
    const f32x4* q = (const f32x4*)((const float*)p + i);
    f32x4 u0 = q[0], u1 = q[1];
#pragma unroll
    for (int j = 0; j < 4; ++j) {
      float a = u0[j], b = u1[j];
      __bf16 ah = (__bf16)a, bh = (__bf16)b;
      hi[j] = ah; hi[4 + j] = bh;
      lo[j] = (__bf16)(a - (float)ah); lo[4 + j] = (__bf16)(b - (float)bh);
    }
  } else {
    hi = *(const bf16x8*)((const __hip_bfloat16*)p + i);
#pragma unroll
    for (int j = 0; j < 8; ++j) lo[j] = (__bf16)0.0f;
  }
}
DEV bf16x8 load8(const __hip_bfloat16* p) {
  return *reinterpret_cast<const bf16x8*>(p);
}

constexpr float L2E = 1.44269504088896f;
DEV float sigm(float x) {
  return __builtin_amdgcn_rcpf(1.0f + __builtin_amdgcn_exp2f(-L2E * x));
}
DEV float tanh_(float x) {
  return 2.0f * __builtin_amdgcn_rcpf(1.0f + __builtin_amdgcn_exp2f(-2.0f * L2E * x)) - 1.0f;
}

// ---- pack W_k (32x1024) + W_r (256x1024) into bf16 hi/lo B-frag order ------
__global__ __launch_bounds__(256) void pack_w(const void* __restrict__ wk,
                                              const void* __restrict__ wr,
                                              const void* __restrict__ bl,
                                              __hip_bfloat16* __restrict__ dhi,
                                              __hip_bfloat16* __restrict__ dlo) {
  const bool f32 = is_f32(bl);
  int idx = blockIdx.x * 256 + threadIdx.x;
  if (idx >= 9 * 64 * 64) return;
  int lane = idx & 63, tile = idx >> 6;
  int nt = tile & 63, ks = tile >> 6;
  int kb = ks * 32 + ((lane >> 4) << 3);
  int n  = (nt << 4) + (lane & 15);
#pragma unroll
  for (int j = 0; j < 8; ++j) {
    int k = kb + j;
    float v = (k < DE) ? ldf(wk, (size_t)k * NG + n, f32)
                       : ldf(wr, (size_t)(k - DE) * NG + n, f32);
    __hip_bfloat16 h, l;
    split2(v, h, l);
    dhi[idx * 8 + j] = h;
    dlo[idx * 8 + j] = l;
  }
}

__global__ __launch_bounds__(256) void pack_e(const void* __restrict__ we,
                                              const void* __restrict__ bl,
                                              __hip_bfloat16* __restrict__ dhi,
                                              __hip_bfloat16* __restrict__ dlo) {
  const bool f32 = is_f32(bl);
  int idx = blockIdx.x * 256 + threadIdx.x;
  if (idx >= 16 * 16 * 64) return;
  int lane = idx & 63, tile = idx >> 6;
  int nt = tile & 15, ks = tile >> 4;
  int kb = ks * 32 + ((lane >> 4) << 3);
  int n  = (nt << 4) + (lane & 15);
#pragma unroll
  for (int j = 0; j < 8; ++j) {
    float v = ldf(we, (size_t)(kb + j) * HD + n, f32);
    __hip_bfloat16 h, l;
    split2(v, h, l);
    dhi[idx * 8 + j] = h;
    dlo[idx * 8 + j] = l;
  }
}

// ---- main persistent LSTM kernel -------------------------------------------
// xh as A-fragments: tile (mt,ks) at [(mt*9+ks)*TS], lane-contiguous 16B/lane.
// A[m][k]: mt=m>>4, ks=k>>5, lane=(m&15)|(((k>>3)&3)<<4), slot=k&7.
// Wave w (0..15) owns hidden cols [16w,16w+16) across all 4 gates.
__global__ __launch_bounds__(1024) void lstm_main(
    const void* __restrict__ enc,
    const void* __restrict__ fx,
    const void* __restrict__ wemb,
    const void* __restrict__ bemb,
    const void* __restrict__ benc,
    const void* __restrict__ blstm,
    const void* __restrict__ wred,
    const void* __restrict__ bredp,
    const __hip_bfloat16* __restrict__ pWhi,
    const __hip_bfloat16* __restrict__ pWlo,
    const __hip_bfloat16* __restrict__ pEhi,
    const __hip_bfloat16* __restrict__ pElo,
    const int* __restrict__ dlen,
    void* __restrict__ out) {
  __shared__ __align__(16) __hip_bfloat16 fragHi[4 * NKT * TS];  // 38016 B
  __shared__ __align__(16) __hip_bfloat16 fragLo[4 * NKT * TS];  // 38016 B
  __shared__ __align__(16) float wredf[HD];

  const bool f32 = is_f32(blstm);
  const int tid  = threadIdx.x;
  const int w    = tid >> 6;          // wave 0..15
  const int lane = tid & 63;
  const int q    = lane >> 4;
  const int cl   = lane & 15;
  const int r0   = blockIdx.x * 64;
  int Tn = dlen[0];
  if (Tn < 1 || Tn > TT) Tn = TT;

  const int aoff = lane * 8;          // A-frag read base (elems)
  // h-write: col c = 16w+cl -> k = 32+c; ks = 1+(w>>1), kk = (w&1)*16+cl;
  // idx = (mt*9+ks)*TS + [(q*4+r) + 16*((w&1)*2+(cl>>3))]*8 + (cl&7)
  const int hwbase = (1 + (w >> 1)) * TS + q * 32 +
                     128 * ((w & 1) * 2 + (cl >> 3)) + (cl & 7);

  // x-update mapping: row = tid>>4, c0 = (tid&15)*2 (2 cols/thread)
  const int xrow  = tid >> 4;
  const int xc0   = (tid & 15) * 2;
  const int xbase = (xrow >> 4) * 9 * TS +
                    ((xrow & 15) + 16 * (xc0 >> 3)) * 8 + (xc0 & 7);
  float wembf[2], bembf[2];
#pragma unroll
  for (int i = 0; i < 2; ++i) {
    wembf[i] = ldf(wemb, xc0 + i, f32);
    bembf[i] = ldf(bemb, xc0 + i, f32);
  }
  if (tid < HD) wredf[tid] = ldf(wred, tid, f32);
  const float bredf = ldf(bredp, 0, f32);

  float gbias[4];
#pragma unroll
  for (int g = 0; g < 4; ++g)
    gbias[g] = ldf(blstm, g * HD + w * 16 + cl, f32);

  // ---- Phase 1: h0 = enc @ W_enc + b_enc (3-product hi/lo, K=512) ----
  f32x4 acc0[4];
  {
    float be = ldf(benc, w * 16 + cl, f32);
#pragma unroll
    for (int mt = 0; mt < 4; ++mt) acc0[mt] = (f32x4){be, be, be, be};
  }
#pragma unroll 1
  for (int ks = 0; ks < ENC / 32; ++ks) {
    size_t fo = ((size_t)(ks * 16 + w) * 64 + lane) * 8;
    bf16x8 bh  = load8(pEhi + fo);
    bf16x8 bl2 = load8(pElo + fo);
#pragma unroll
    for (int mt = 0; mt < 4; ++mt) {
      bf16x8 ah, al;
      ld8cvt2(enc, (size_t)(r0 + mt * 16 + cl) * ENC + ks * 32 + q * 8, f32, ah, al);
      acc0[mt] = __builtin_amdgcn_mfma_f32_16x16x32_bf16(ah, bh,  acc0[mt], 0, 0, 0);
      acc0[mt] = __builtin_amdgcn_mfma_f32_16x16x32_bf16(al, bh,  acc0[mt], 0, 0, 0);
      acc0[mt] = __builtin_amdgcn_mfma_f32_16x16x32_bf16(ah, bl2, acc0[mt], 0, 0, 0);
    }
  }
  // h0 write into frag layout (C/D: col=cl, row=q*4+r)
#pragma unroll
  for (int mt = 0; mt < 4; ++mt)
#pragma unroll
    for (int r = 0; r < 4; ++r) {
      int idx = mt * 9 * TS + hwbase + r * 8;
      __hip_bfloat16 h, l;
      split2(acc0[mt][r], h, l);
      fragHi[idx] = h;
      fragLo[idx] = l;
    }
  // x0 = fx * W_emb + b_emb (ks tile 0): 2 cols/thread
  {
    float fv = ldf(fx, r0 + xrow, f32);
    bf16x2 hv, lv;
#pragma unroll
    for (int i = 0; i < 2; ++i) {
      __hip_bfloat16 h, l;
      split2(fv * wembf[i] + bembf[i], h, l);
      hv[i] = h; lv[i] = l;
    }
    *(bf16x2*)&fragHi[xbase] = hv;
    *(bf16x2*)&fragLo[xbase] = lv;
  }

  f32x4 cst[4];
#pragma unroll
  for (int mt = 0; mt < 4; ++mt) cst[mt] = (f32x4){0.f, 0.f, 0.f, 0.f};

  __syncthreads();

  const __hip_bfloat16* wbase = pWhi + ((size_t)w * 64 + lane) * 8;

  // ---- Phase 2: T-step recurrence ----
#pragma unroll 1
  for (int t = 0; t < Tn; ++t) {
    f32x4 acc[4][4];   // [m-tile][gate]
#pragma unroll
    for (int mt = 0; mt < 4; ++mt)
#pragma unroll
      for (int g = 0; g < 4; ++g) {
        float bb = gbias[g];
        acc[mt][g] = (f32x4){bb, bb, bb, bb};
      }

    // ---- ks = 0 peeled: hi + A-lo + W_k-lo products ----
#pragma unroll
    for (int g = 0; g < 4; ++g) {
      bf16x8 b   = load8(wbase + (size_t)(g * 16) * 512);
      bf16x8 bl2 = load8(pWlo + ((size_t)(g * 16 + w) * 64 + lane) * 8);
#pragma unroll
      for (int mt = 0; mt < 4; ++mt) {
        bf16x8 ah = load8(&fragHi[(mt * 9) * TS + aoff]);
        bf16x8 al = load8(&fragLo[(mt * 9) * TS + aoff]);
        acc[mt][g] = __builtin_amdgcn_mfma_f32_16x16x32_bf16(ah, b,   acc[mt][g], 0, 0, 0);
        acc[mt][g] = __builtin_amdgcn_mfma_f32_16x16x32_bf16(al, b,   acc[mt][g], 0, 0, 0);
        acc[mt][g] = __builtin_amdgcn_mfma_f32_16x16x32_bf16(ah, bl2, acc[mt][g], 0, 0, 0);
      }
    }

    // ---- ks = 1..8 rolled, 1-deep B prefetch ----
    bf16x8 bcur[4];
#pragma unroll
    for (int g = 0; g < 4; ++g)
      bcur[g] = load8(wbase + (size_t)(64 + g * 16) * 512);

#pragma unroll 1
    for (int ks = 1; ks < 8; ++ks) {
      bf16x8 bnext[4];
#pragma unroll
      for (int g = 0; g < 4; ++g)
        bnext[g] = load8(wbase + (size_t)((ks + 1) * 64 + g * 16) * 512);
#pragma unroll
      for (int mt = 0; mt < 4; ++mt) {
        bf16x8 ah = load8(&fragHi[(mt * 9 + ks) * TS + aoff]);
        bf16x8 al = load8(&fragLo[(mt * 9 + ks) * TS + aoff]);
#pragma unroll
        for (int g = 0; g < 4; ++g) {
          acc[mt][g] = __builtin_amdgcn_mfma_f32_16x16x32_bf16(ah, bcur[g], acc[mt][g], 0, 0, 0);
          acc[mt][g] = __builtin_amdgcn_mfma_f32_16x16x32_bf16(al, bcur[g], acc[mt][g], 0, 0, 0);
        }
      }
#pragma unroll
      for (int g = 0; g < 4; ++g) bcur[g] = bnext[g];
    }
    // epilogue ks = 8
#pragma unroll
    for (int mt = 0; mt < 4; ++mt) {
      bf16x8 ah = load8(&fragHi[(mt * 9 + 8) * TS + aoff]);
      bf16x8 al = load8(&fragLo[(mt * 9 + 8) * TS + aoff]);
#pragma unroll
      for (int g = 0; g < 4; ++g) {
        acc[mt][g] = __builtin_amdgcn_mfma_f32_16x16x32_bf16(ah, bcur[g], acc[mt][g], 0, 0, 0);
        acc[mt][g] = __builtin_amdgcn_mfma_f32_16x16x32_bf16(al, bcur[g], acc[mt][g], 0, 0, 0);
      }
    }

    // cell update (results buffered; written after read barrier)
    float hnv[16];
#pragma unroll
    for (int mt = 0; mt < 4; ++mt)
#pragma unroll
      for (int r = 0; r < 4; ++r) {
        float gi = acc[mt][0][r];
        float gf = acc[mt][1][r];
        float gc = acc[mt][2][r];
        float go = acc[mt][3][r];
        float cn = sigm(gf) * cst[mt][r] + sigm(gi) * tanh_(gc);
        cst[mt][r] = cn;
        hnv[mt * 4 + r] = sigm(go) * tanh_(cn);
      }
    __syncthreads();   // all waves done reading frags

    // write h_new hi/lo into frag layout
#pragma unroll
    for (int mt = 0; mt < 4; ++mt)
#pragma unroll
      for (int r = 0; r < 4; ++r) {
        int idx = mt * 9 * TS + hwbase + r * 8;
        __hip_bfloat16 h, l;
        split2(hnv[mt * 4 + r], h, l);
        fragHi[idx] = h;
        fragLo[idx] = l;
      }
    __syncthreads();   // h_new visible

    // y = h_new @ W_red + b_red  (16 threads/row, 16 cols each) + x-update
    {
      int row = xrow, part = tid & 15;
      int mt = row >> 4;
      int ks = 1 + (part >> 1);
      int lane2 = (row & 15) + 16 * ((part & 1) * 2);
      int base = (mt * 9 + ks) * TS + lane2 * 8;
      float sum = 0.f;
#pragma unroll
      for (int jj = 0; jj < 2; ++jj) {
        bf16x8 hv = load8(&fragHi[base + jj * 128]);
        bf16x8 lv = load8(&fragLo[base + jj * 128]);
#pragma unroll
        for (int j = 0; j < 8; ++j)
          sum += ((float)hv[j] + (float)lv[j]) * wredf[part * 16 + jj * 8 + j];
      }
      sum += __shfl_xor(sum, 1);
      sum += __shfl_xor(sum, 2);
      sum += __shfl_xor(sum, 4);
      sum += __shfl_xor(sum, 8);
      float y = sum + bredf;       // full sum in all 16 threads
      if (part == 0) {
        size_t oi = (size_t)(r0 + row) * TT + t;
        if (f32) ((float*)out)[oi] = y;
        else     ((__hip_bfloat16*)out)[oi] = __float2bfloat16(y);
      }
      // x_next = y * W_emb + b_emb (2 cols/thread, same thread group)
      bf16x2 hv2, lv2;
#pragma unroll
      for (int i = 0; i < 2; ++i) {
        __hip_bfloat16 h, l;
        split2(y * wembf[i] + bembf[i], h, l);
        hv2[i] = h; lv2[i] = l;
      }
      *(bf16x2*)&fragHi[xbase] = hv2;
      *(bf16x2*)&fragLo[xbase] = lv2;
    }
    __syncthreads();   // frags ready for next step
  }
}

extern "C" void kernel_launch(void* const* d_in, const int* in_sizes, int n_in,
                              void* d_out, int out_size, void* d_ws, size_t ws_size,
                              hipStream_t stream) {
  const void* enc  = d_in[0];
  const void* fx   = d_in[1];
  const void* wemb = d_in[2];
  const void* bemb = d_in[3];
  const void* wenc = d_in[4];
  const void* benc = d_in[5];
  const void* wk   = d_in[6];
  const void* wr   = d_in[7];
  const void* bl   = d_in[8];
  const void* wred = d_in[9];
  const void* bred = d_in[10];
  const int* dlen  = (const int*)d_in[11];

  // ws layout (bf16): pWhi 294912 | pWlo 294912 | pEhi 131072 | pElo 131072
  __hip_bfloat16* pWhi = (__hip_bfloat16*)d_ws;
  __hip_bfloat16* pWlo = pWhi + 9 * 64 * 64 * 8;
  __hip_bfloat16* pEhi = pWlo + 9 * 64 * 64 * 8;
  __hip_bfloat16* pElo = pEhi + 16 * 16 * 64 * 8;

  pack_w<<<144, 256, 0, stream>>>(wk, wr, bl, pWhi, pWlo);
  pack_e<<<64, 256, 0, stream>>>(wenc, bl, pEhi, pElo);

  int nblocks = in_sizes[1] / 64;   // 16384/64 = 256
  lstm_main<<<nblocks, 1024, 0, stream>>>(enc, fx, wemb, bemb, benc, bl, wred,
                                          bred, pWhi, pWlo, pEhi, pElo, dlen, d_out);
}

// Round 9
// 1523.093 us; speedup vs baseline: 1.1634x; 1.1634x over previous
//
#include <hip/hip_runtime.h>
#include <hip/hip_bf16.h>
#include <math.h>

// DecoderLSTM: B=16384, ENC=512, H=256, DE=32, T=64. f32 in/out (runtime-
// detected via b_lstm pattern; bf16 fallback kept).
// Persistent: 256 blocks x 1024 threads (16 waves), one block per 64-row tile.
// Precision: bf16x2 (hi/lo) A operand + hi/lo W_enc + hi/lo W_k (ks=0).
// R9: R8 spilled (compiler saw 2-blocks-by-LDS -> 64-reg cap, 1.16 GB scratch).
//   - amdgpu_waves_per_eu(4,4): pin 4 waves/SIMD -> 128-reg budget (grid=256
//     gives exactly 1 block/CU anyway).
//   - dropped bnext prefetch (bcur loaded at loop top; 4-wave TLP hides L2
//     latency) -> per-wave demand ~130 regs, fits the 128 cap w/ acc in AGPRs.

typedef __bf16 bf16x8 __attribute__((ext_vector_type(8)));
typedef __bf16 bf16x2 __attribute__((ext_vector_type(2)));
typedef float f32x4 __attribute__((ext_vector_type(4)));

#define DEV __device__ __forceinline__

constexpr int ENC = 512;
constexpr int HD  = 256;
constexpr int DE  = 32;
constexpr int TT  = 64;
constexpr int NG  = 4 * HD;    // 1024 gate cols
constexpr int NKT = 9;         // K tiles (288 / 32)
constexpr int TS  = 528;       // frag tile stride elems (64*8 + 16 pad)

DEV bool is_f32(const void* blstm) {
  return ((const unsigned*)blstm)[256] == 0x3F800000u;
}
DEV float ldf(const void* p, size_t i, bool f32) {
  return f32 ? ((const float*)p)[i]
             : __bfloat162float(((const __hip_bfloat16*)p)[i]);
}
DEV void split2(float v, __hip_bfloat16& hi, __hip_bfloat16& lo) {
  hi = __float2bfloat16(v);
  lo = __float2bfloat16(v - __bfloat162float(hi));
}
DEV void ld8cvt2(const void* p, size_t i, bool f32, bf16x8& hi, bf16x8& lo) {
  if (f32) {
    const f32x4* q = (const f32x4*)((const float*)p + i);
    f32x4 u0 = q[0], u1 = q[1];
#pragma unroll
    for (int j = 0; j < 4; ++j) {
      float a = u0[j], b = u1[j];
      __bf16 ah = (__bf16)a, bh = (__bf16)b;
      hi[j] = ah; hi[4 + j] = bh;
      lo[j] = (__bf16)(a - (float)ah); lo[4 + j] = (__bf16)(b - (float)bh);
    }
  } else {
    hi = *(const bf16x8*)((const __hip_bfloat16*)p + i);
#pragma unroll
    for (int j = 0; j < 8; ++j) lo[j] = (__bf16)0.0f;
  }
}
DEV bf16x8 load8(const __hip_bfloat16* p) {
  return *reinterpret_cast<const bf16x8*>(p);
}

constexpr float L2E = 1.44269504088896f;
DEV float sigm(float x) {
  return __builtin_amdgcn_rcpf(1.0f + __builtin_amdgcn_exp2f(-L2E * x));
}
DEV float tanh_(float x) {
  return 2.0f * __builtin_amdgcn_rcpf(1.0f + __builtin_amdgcn_exp2f(-2.0f * L2E * x)) - 1.0f;
}

// ---- pack W_k (32x1024) + W_r (256x1024) into bf16 hi/lo B-frag order ------
__global__ __launch_bounds__(256) void pack_w(const void* __restrict__ wk,
                                              const void* __restrict__ wr,
                                              const void* __restrict__ bl,
                                              __hip_bfloat16* __restrict__ dhi,
                                              __hip_bfloat16* __restrict__ dlo) {
  const bool f32 = is_f32(bl);
  int idx = blockIdx.x * 256 + threadIdx.x;
  if (idx >= 9 * 64 * 64) return;
  int lane = idx & 63, tile = idx >> 6;
  int nt = tile & 63, ks = tile >> 6;
  int kb = ks * 32 + ((lane >> 4) << 3);
  int n  = (nt << 4) + (lane & 15);
#pragma unroll
  for (int j = 0; j < 8; ++j) {
    int k = kb + j;
    float v = (k < DE) ? ldf(wk, (size_t)k * NG + n, f32)
                       : ldf(wr, (size_t)(k - DE) * NG + n, f32);
    __hip_bfloat16 h, l;
    split2(v, h, l);
    dhi[idx * 8 + j] = h;
    dlo[idx * 8 + j] = l;
  }
}

__global__ __launch_bounds__(256) void pack_e(const void* __restrict__ we,
                                              const void* __restrict__ bl,
                                              __hip_bfloat16* __restrict__ dhi,
                                              __hip_bfloat16* __restrict__ dlo) {
  const bool f32 = is_f32(bl);
  int idx = blockIdx.x * 256 + threadIdx.x;
  if (idx >= 16 * 16 * 64) return;
  int lane = idx & 63, tile = idx >> 6;
  int nt = tile & 15, ks = tile >> 4;
  int kb = ks * 32 + ((lane >> 4) << 3);
  int n  = (nt << 4) + (lane & 15);
#pragma unroll
  for (int j = 0; j < 8; ++j) {
    float v = ldf(we, (size_t)(kb + j) * HD + n, f32);
    __hip_bfloat16 h, l;
    split2(v, h, l);
    dhi[idx * 8 + j] = h;
    dlo[idx * 8 + j] = l;
  }
}

// ---- main persistent LSTM kernel -------------------------------------------
// xh as A-fragments: tile (mt,ks) at [(mt*9+ks)*TS], lane-contiguous 16B/lane.
// A[m][k]: mt=m>>4, ks=k>>5, lane=(m&15)|(((k>>3)&3)<<4), slot=k&7.
// Wave w (0..15) owns hidden cols [16w,16w+16) across all 4 gates.
__global__ __launch_bounds__(1024)
__attribute__((amdgpu_waves_per_eu(4, 4)))
void lstm_main(
    const void* __restrict__ enc,
    const void* __restrict__ fx,
    const void* __restrict__ wemb,
    const void* __restrict__ bemb,
    const void* __restrict__ benc,
    const void* __restrict__ blstm,
    const void* __restrict__ wred,
    const void* __restrict__ bredp,
    const __hip_bfloat16* __restrict__ pWhi,
    const __hip_bfloat16* __restrict__ pWlo,
    const __hip_bfloat16* __restrict__ pEhi,
    const __hip_bfloat16* __restrict__ pElo,
    const int* __restrict__ dlen,
    void* __restrict__ out) {
  __shared__ __align__(16) __hip_bfloat16 fragHi[4 * NKT * TS];  // 38016 B
  __shared__ __align__(16) __hip_bfloat16 fragLo[4 * NKT * TS];  // 38016 B
  __shared__ __align__(16) float wredf[HD];

  const bool f32 = is_f32(blstm);
  const int tid  = threadIdx.x;
  const int w    = tid >> 6;          // wave 0..15
  const int lane = tid & 63;
  const int q    = lane >> 4;
  const int cl   = lane & 15;
  const int r0   = blockIdx.x * 64;
  int Tn = dlen[0];
  if (Tn < 1 || Tn > TT) Tn = TT;

  const int aoff = lane * 8;          // A-frag read base (elems)
  // h-write: col c = 16w+cl -> k = 32+c; ks = 1+(w>>1), kk = (w&1)*16+cl;
  // idx = (mt*9+ks)*TS + [(q*4+r) + 16*((w&1)*2+(cl>>3))]*8 + (cl&7)
  const int hwbase = (1 + (w >> 1)) * TS + q * 32 +
                     128 * ((w & 1) * 2 + (cl >> 3)) + (cl & 7);

  // x-update mapping: row = tid>>4, c0 = (tid&15)*2 (2 cols/thread)
  const int xrow  = tid >> 4;
  const int xc0   = (tid & 15) * 2;
  const int xbase = (xrow >> 4) * 9 * TS +
                    ((xrow & 15) + 16 * (xc0 >> 3)) * 8 + (xc0 & 7);
  float wembf[2], bembf[2];
#pragma unroll
  for (int i = 0; i < 2; ++i) {
    wembf[i] = ldf(wemb, xc0 + i, f32);
    bembf[i] = ldf(bemb, xc0 + i, f32);
  }
  if (tid < HD) wredf[tid] = ldf(wred, tid, f32);
  const float bredf = ldf(bredp, 0, f32);

  float gbias[4];
#pragma unroll
  for (int g = 0; g < 4; ++g)
    gbias[g] = ldf(blstm, g * HD + w * 16 + cl, f32);

  // ---- Phase 1: h0 = enc @ W_enc + b_enc (3-product hi/lo, K=512) ----
  f32x4 acc0[4];
  {
    float be = ldf(benc, w * 16 + cl, f32);
#pragma unroll
    for (int mt = 0; mt < 4; ++mt) acc0[mt] = (f32x4){be, be, be, be};
  }
#pragma unroll 1
  for (int ks = 0; ks < ENC / 32; ++ks) {
    size_t fo = ((size_t)(ks * 16 + w) * 64 + lane) * 8;
    bf16x8 bh  = load8(pEhi + fo);
    bf16x8 bl2 = load8(pElo + fo);
#pragma unroll
    for (int mt = 0; mt < 4; ++mt) {
      bf16x8 ah, al;
      ld8cvt2(enc, (size_t)(r0 + mt * 16 + cl) * ENC + ks * 32 + q * 8, f32, ah, al);
      acc0[mt] = __builtin_amdgcn_mfma_f32_16x16x32_bf16(ah, bh,  acc0[mt], 0, 0, 0);
      acc0[mt] = __builtin_amdgcn_mfma_f32_16x16x32_bf16(al, bh,  acc0[mt], 0, 0, 0);
      acc0[mt] = __builtin_amdgcn_mfma_f32_16x16x32_bf16(ah, bl2, acc0[mt], 0, 0, 0);
    }
  }
  // h0 write into frag layout (C/D: col=cl, row=q*4+r)
#pragma unroll
  for (int mt = 0; mt < 4; ++mt)
#pragma unroll
    for (int r = 0; r < 4; ++r) {
      int idx = mt * 9 * TS + hwbase + r * 8;
      __hip_bfloat16 h, l;
      split2(acc0[mt][r], h, l);
      fragHi[idx] = h;
      fragLo[idx] = l;
    }
  // x0 = fx * W_emb + b_emb (ks tile 0): 2 cols/thread
  {
    float fv = ldf(fx, r0 + xrow, f32);
    bf16x2 hv, lv;
#pragma unroll
    for (int i = 0; i < 2; ++i) {
      __hip_bfloat16 h, l;
      split2(fv * wembf[i] + bembf[i], h, l);
      hv[i] = h; lv[i] = l;
    }
    *(bf16x2*)&fragHi[xbase] = hv;
    *(bf16x2*)&fragLo[xbase] = lv;
  }

  f32x4 cst[4];
#pragma unroll
  for (int mt = 0; mt < 4; ++mt) cst[mt] = (f32x4){0.f, 0.f, 0.f, 0.f};

  __syncthreads();

  const __hip_bfloat16* wbase = pWhi + ((size_t)w * 64 + lane) * 8;

  // ---- Phase 2: T-step recurrence ----
#pragma unroll 1
  for (int t = 0; t < Tn; ++t) {
    f32x4 acc[4][4];   // [m-tile][gate]
#pragma unroll
    for (int mt = 0; mt < 4; ++mt)
#pragma unroll
      for (int g = 0; g < 4; ++g) {
        float bb = gbias[g];
        acc[mt][g] = (f32x4){bb, bb, bb, bb};
      }

    // ---- ks = 0 peeled: hi + A-lo + W_k-lo products ----
#pragma unroll
    for (int g = 0; g < 4; ++g) {
      bf16x8 b   = load8(wbase + (size_t)(g * 16) * 512);
      bf16x8 bl2 = load8(pWlo + ((size_t)(g * 16 + w) * 64 + lane) * 8);
#pragma unroll
      for (int mt = 0; mt < 4; ++mt) {
        bf16x8 ah = load8(&fragHi[(mt * 9) * TS + aoff]);
        bf16x8 al = load8(&fragLo[(mt * 9) * TS + aoff]);
        acc[mt][g] = __builtin_amdgcn_mfma_f32_16x16x32_bf16(ah, b,   acc[mt][g], 0, 0, 0);
        acc[mt][g] = __builtin_amdgcn_mfma_f32_16x16x32_bf16(al, b,   acc[mt][g], 0, 0, 0);
        acc[mt][g] = __builtin_amdgcn_mfma_f32_16x16x32_bf16(ah, bl2, acc[mt][g], 0, 0, 0);
      }
    }

    // ---- ks = 1..8 rolled, bcur loaded at loop top (TLP hides L2 latency) --
#pragma unroll 1
    for (int ks = 1; ks < 9; ++ks) {
      bf16x8 bcur[4];
#pragma unroll
      for (int g = 0; g < 4; ++g)
        bcur[g] = load8(wbase + (size_t)(ks * 64 + g * 16) * 512);
#pragma unroll
      for (int mt = 0; mt < 4; ++mt) {
        bf16x8 ah = load8(&fragHi[(mt * 9 + ks) * TS + aoff]);
        bf16x8 al = load8(&fragLo[(mt * 9 + ks) * TS + aoff]);
#pragma unroll
        for (int g = 0; g < 4; ++g) {
          acc[mt][g] = __builtin_amdgcn_mfma_f32_16x16x32_bf16(ah, bcur[g], acc[mt][g], 0, 0, 0);
          acc[mt][g] = __builtin_amdgcn_mfma_f32_16x16x32_bf16(al, bcur[g], acc[mt][g], 0, 0, 0);
        }
      }
    }

    // cell update (results buffered; written after read barrier)
    float hnv[16];
#pragma unroll
    for (int mt = 0; mt < 4; ++mt)
#pragma unroll
      for (int r = 0; r < 4; ++r) {
        float gi = acc[mt][0][r];
        float gf = acc[mt][1][r];
        float gc = acc[mt][2][r];
        float go = acc[mt][3][r];
        float cn = sigm(gf) * cst[mt][r] + sigm(gi) * tanh_(gc);
        cst[mt][r] = cn;
        hnv[mt * 4 + r] = sigm(go) * tanh_(cn);
      }
    __syncthreads();   // all waves done reading frags

    // write h_new hi/lo into frag layout
#pragma unroll
    for (int mt = 0; mt < 4; ++mt)
#pragma unroll
      for (int r = 0; r < 4; ++r) {
        int idx = mt * 9 * TS + hwbase + r * 8;
        __hip_bfloat16 h, l;
        split2(hnv[mt * 4 + r], h, l);
        fragHi[idx] = h;
        fragLo[idx] = l;
      }
    __syncthreads();   // h_new visible

    // y = h_new @ W_red + b_red  (16 threads/row, 16 cols each) + x-update
    {
      int row = xrow, part = tid & 15;
      int mt = row >> 4;
      int ks = 1 + (part >> 1);
      int lane2 = (row & 15) + 16 * ((part & 1) * 2);
      int base = (mt * 9 + ks) * TS + lane2 * 8;
      float sum = 0.f;
#pragma unroll
      for (int jj = 0; jj < 2; ++jj) {
        bf16x8 hv = load8(&fragHi[base + jj * 128]);
        bf16x8 lv = load8(&fragLo[base + jj * 128]);
#pragma unroll
        for (int j = 0; j < 8; ++j)
          sum += ((float)hv[j] + (float)lv[j]) * wredf[part * 16 + jj * 8 + j];
      }
      sum += __shfl_xor(sum, 1);
      sum += __shfl_xor(sum, 2);
      sum += __shfl_xor(sum, 4);
      sum += __shfl_xor(sum, 8);
      float y = sum + bredf;       // full sum in all 16 threads
      if (part == 0) {
        size_t oi = (size_t)(r0 + row) * TT + t;
        if (f32) ((float*)out)[oi] = y;
        else     ((__hip_bfloat16*)out)[oi] = __float2bfloat16(y);
      }
      // x_next = y * W_emb + b_emb (2 cols/thread, same thread group)
      bf16x2 hv2, lv2;
#pragma unroll
      for (int i = 0; i < 2; ++i) {
        __hip_bfloat16 h, l;
        split2(y * wembf[i] + bembf[i], h, l);
        hv2[i] = h; lv2[i] = l;
      }
      *(bf16x2*)&fragHi[xbase] = hv2;
      *(bf16x2*)&fragLo[xbase] = lv2;
    }
    __syncthreads();   // frags ready for next step
  }
}

extern "C" void kernel_launch(void* const* d_in, const int* in_sizes, int n_in,
                              void* d_out, int out_size, void* d_ws, size_t ws_size,
                              hipStream_t stream) {
  const void* enc  = d_in[0];
  const void* fx   = d_in[1];
  const void* wemb = d_in[2];
  const void* bemb = d_in[3];
  const void* wenc = d_in[4];
  const void* benc = d_in[5];
  const void* wk   = d_in[6];
  const void* wr   = d_in[7];
  const void* bl   = d_in[8];
  const void* wred = d_in[9];
  const void* bred = d_in[10];
  const int* dlen  = (const int*)d_in[11];

  // ws layout (bf16): pWhi 294912 | pWlo 294912 | pEhi 131072 | pElo 131072
  __hip_bfloat16* pWhi = (__hip_bfloat16*)d_ws;
  __hip_bfloat16* pWlo = pWhi + 9 * 64 * 64 * 8;
  __hip_bfloat16* pEhi = pWlo + 9 * 64 * 64 * 8;
  __hip_bfloat16* pElo = pEhi + 16 * 16 * 64 * 8;

  pack_w<<<144, 256, 0, stream>>>(wk, wr, bl, pWhi, pWlo);
  pack_e<<<64, 256, 0, stream>>>(wenc, bl, pEhi, pElo);

  int nblocks = in_sizes[1] / 64;   // 16384/64 = 256
  lstm_main<<<nblocks, 1024, 0, stream>>>(enc, fx, wemb, bemb, benc, bl, wred,
                                          bred, pWhi, pWlo, pEhi, pElo, dlen, d_out);
}